// Round 6
// baseline (121.998 us; speedup 1.0000x reference)
//
#include <hip/hip_runtime.h>
#include <stdint.h>

#define B_ROWS 4096
#define NTOT   8192
#define D0     2048
#define D1     128
#define TAU    80.0f   // fp8 filter: quantization error on l2 is <~32; true-candidate
                       // threshold of interest is l2<~48 (k1=e^-28); margin is huge.

// ---- workspace layout (bytes) ----
#define OFF_ACC   0        // double  signed sum of OFF-DIAGONAL joint entries
#define OFF_S0    8        // double  sum of squared f0 entries
#define OFF_MDONE 16       // unsigned m0-ready counter (cold path grid barrier)
#define OFF_CNT   20       // unsigned candidate count
#define OFF_DONE  24       // unsigned phaseB completion counter
#define OFF_M0    32       // float[2048] column sums of f0
#define OFF_SQ1   8320     // float[8192] row sq-norms of f1
#define OFF_T1    41216    // fp8[8192*128] e4m3 copy of f1 (1 MB)
#define OFF_CAND  2138368  // uint2[] candidate pairs
#define ZERO_WORDS 2056    // bytes 0..8223: header + M0

typedef float f32x4 __attribute__((ext_vector_type(4)));
typedef float f32x2 __attribute__((ext_vector_type(2)));
typedef long i64;

#define LDST 136   // bytes per LDS row (128 data + 8 pad; multiple of 8)

// ---- Pass 0a: fp8 convert f1 + row squared norms + ws header zeroing -----
// t1 written NON-TEMPORAL and CLEAN; src1/tar1 read NON-TEMPORAL (single
// use -> skip LLC allocate, avoid forced eviction of dirty poison lines).
__global__ void p0a(const float* __restrict__ src1, const float* __restrict__ tar1, char* __restrict__ ws) {
    if (blockIdx.x == 0) {
        unsigned* w = (unsigned*)ws;
        for (int i = threadIdx.x; i < ZERO_WORDS; i += 256) w[i] = 0;
    }
    int wave = threadIdx.x >> 6, lane = threadIdx.x & 63;
    int row = blockIdx.x * 4 + wave;
    const f32x2* rp = (const f32x2*)(row < B_ROWS ? src1 + (size_t)row * D1
                                                  : tar1 + (size_t)(row - B_ROWS) * D1);
    f32x2 v = __builtin_nontemporal_load(&rp[lane]);
    float sq = v.x * v.x + v.y * v.y;
    #pragma unroll
    for (int off = 32; off; off >>= 1) sq += __shfl_down(sq, off);
    if (lane == 0) ((float*)(ws + OFF_SQ1))[row] = sq;
    int pk = __builtin_amdgcn_cvt_pk_fp8_f32(v.x, v.y, 0, false);  // 2 e4m3 bytes
    __builtin_nontemporal_store((unsigned short)(pk & 0xffff),
        (unsigned short*)(ws + OFF_T1 + (size_t)row * 128 + lane * 2));
}

// ---- Phase A: pairwise l2 on feature-1 via fp8 MFMA, emit candidates -----
// 256x256 tiles: 528 upper-triangle blocks (bj >= bi) of 512 threads.
// ~1 staging generation per CU (528 blocks / 2-per-CU / 256 CUs), single
// barrier, 128 MFMAs/wave (16x16x32_fp8_fp8). l2 = sq_f32[a]+sq_f32[b]-2*dot8.
// Emits STRICT a<b pairs only; diagonal contributes constant 8192*5.
__global__ __launch_bounds__(512, 2) void phaseA(char* __restrict__ ws, unsigned cap) {
    // unmap linear tile id -> (bi, bj), bj >= bi, 32x32 tile grid
    int tid = blockIdx.x;
    int bi = (int)((65.0 - sqrt(65.0 * 65.0 - 8.0 * (double)tid)) * 0.5);
    while (((bi + 1) * (65 - (bi + 1))) / 2 <= tid) bi++;
    while ((bi * (65 - bi)) / 2 > tid) bi--;
    int bj = bi + (tid - (bi * (65 - bi)) / 2);

    __shared__ __align__(16) unsigned char At[256 * LDST];
    __shared__ __align__(16) unsigned char Bt[256 * LDST];
    const uint4* t1 = (const uint4*)(ws + OFF_T1);  // 8 uint4 per 128-B row
    int t = threadIdx.x;
    int lane = t & 63, wave = t >> 6;
    int wm = wave & 1, wn = wave >> 1;     // 2 x 4 wave grid: 128-row x 64-col
    int quad = lane >> 4;
    int Abase = bi * 256, Bbase = bj * 256;

    // ---- stage: 2048 16B-chunks per strip, 4 per thread per strip ----
    #pragma unroll
    for (int i = 0; i < 4; i++) {
        int q = t + 512 * i;        // 0..2047
        int r = q >> 3, c = q & 7;  // row (0..255), chunk-in-row
        uint4 va = t1[(size_t)(Abase + r) * 8 + c];
        *(uint4*)(At + r * LDST + c * 16) = va;
        uint4 vb = t1[(size_t)(Bbase + r) * 8 + c];
        *(uint4*)(Bt + r * LDST + c * 16) = vb;
    }
    __syncthreads();

    f32x4 acc[8][4];
    #pragma unroll
    for (int i = 0; i < 8; i++)
        #pragma unroll
        for (int j = 0; j < 4; j++) acc[i][j] = (f32x4){0.f, 0.f, 0.f, 0.f};

    #pragma unroll
    for (int ks = 0; ks < 4; ks++) {
        int koff = ks * 32 + quad * 8;   // byte offset within 128-B data row
        i64 af[8], bf[4];
        #pragma unroll
        for (int mi = 0; mi < 8; mi++) {
            int row = wm * 128 + mi * 16 + (lane & 15);
            af[mi] = *(const i64*)(At + row * LDST + koff);
        }
        #pragma unroll
        for (int nj = 0; nj < 4; nj++) {
            int row = wn * 64 + nj * 16 + (lane & 15);
            bf[nj] = *(const i64*)(Bt + row * LDST + koff);
        }
        #pragma unroll
        for (int mi = 0; mi < 8; mi++)
            #pragma unroll
            for (int nj = 0; nj < 4; nj++)
                acc[mi][nj] = __builtin_amdgcn_mfma_f32_16x16x32_fp8_fp8(
                    af[mi], bf[nj], acc[mi][nj], 0, 0, 0);
    }

    // epilogue: l2 = sq[a]+sq[b]-2*dot ; emit strict a<b pairs below cutoff
    const float* sq1 = (const float*)(ws + OFF_SQ1);
    unsigned* cnt = (unsigned*)(ws + OFF_CNT);
    uint2* cand = (uint2*)(ws + OFF_CAND);
    f32x4 sqa[8];
    #pragma unroll
    for (int mi = 0; mi < 8; mi++)
        sqa[mi] = *(const f32x4*)&sq1[Abase + wm * 128 + mi * 16 + quad * 4];
    #pragma unroll
    for (int nj = 0; nj < 4; nj++) {
        int b = Bbase + wn * 64 + nj * 16 + (lane & 15);
        float sqb = sq1[b];
        #pragma unroll
        for (int mi = 0; mi < 8; mi++) {
            int abase = Abase + wm * 128 + mi * 16 + quad * 4;
            #pragma unroll
            for (int r = 0; r < 4; r++) {
                int a = abase + r;
                float l2 = sqa[mi][r] + sqb - 2.0f * acc[mi][nj][r];
                if (l2 < TAU && a < b) {
                    unsigned idx = atomicAdd(cnt, 1u);
                    if (idx < cap) cand[idx] = make_uint2((unsigned)a, (unsigned)b);
                }
            }
        }
    }
}

// ---- Phase B: exact f32 eval of candidates + bandwidth + final output -----
// Cold path (cnt>0, never on this data) also builds M0/S0 in-kernel (former
// bwk1): 64 blocks each column-sum 128 rows, then device-scope counter spin
// (64 blocks are trivially co-resident on 256 CUs). Last-done block writes
// d_out via done-counter.
__global__ void phaseB(const float* __restrict__ src0, const float* __restrict__ src1,
                       const float* __restrict__ tar0, const float* __restrict__ tar1,
                       char* __restrict__ ws, unsigned cap, float* __restrict__ out) {
    __shared__ double red[4];
    __shared__ float fred[4];
    __shared__ float bws;
    unsigned cnt = *(const unsigned*)(ws + OFF_CNT);   // block-uniform
    if (cnt > cap) cnt = cap;
    int lane = threadIdx.x & 63, wave = threadIdx.x >> 6;
    if (cnt > 0) {
        // ---- build M0 (column sums) + S0 over f0: 128 rows per block ----
        {
            int rbase = blockIdx.x * 128;   // 64 blocks x 128 rows = 8192
            const float4* base = (const float4*)(rbase < B_ROWS ? src0 + (size_t)rbase * D0
                                                                : tar0 + (size_t)(rbase - B_ROWS) * D0);
            float* m0 = (float*)(ws + OFF_M0);
            float sq = 0.f;
            #pragma unroll
            for (int h = 0; h < 2; h++) {
                int d4 = threadIdx.x + h * 256;   // float4-column, 0..511
                float4 cs = {0.f, 0.f, 0.f, 0.f};
                for (int r = 0; r < 128; r++) {
                    float4 v = base[(size_t)r * 512 + d4];
                    cs.x += v.x; cs.y += v.y; cs.z += v.z; cs.w += v.w;
                    sq += v.x * v.x + v.y * v.y + v.z * v.z + v.w * v.w;
                }
                atomicAdd(&m0[d4 * 4 + 0], cs.x);
                atomicAdd(&m0[d4 * 4 + 1], cs.y);
                atomicAdd(&m0[d4 * 4 + 2], cs.z);
                atomicAdd(&m0[d4 * 4 + 3], cs.w);
            }
            #pragma unroll
            for (int off = 32; off; off >>= 1) sq += __shfl_down(sq, off);
            if (lane == 0) fred[wave] = sq;
            __syncthreads();
            if (threadIdx.x == 0) {
                atomicAdd((double*)(ws + OFF_S0),
                          (double)(fred[0] + fred[1] + fred[2] + fred[3]));
                __threadfence();
                atomicAdd((unsigned*)(ws + OFF_MDONE), 1u);
                while (*(volatile unsigned*)(ws + OFF_MDONE) < 64u) { }
            }
            __syncthreads();
            __threadfence();
        }
        // ---- bandwidth0 = (2n*S0 - 2*||m||^2)/(n^2-n)/4 (per-block) ----
        const float* m0 = (const float*)(ws + OFF_M0);
        float s = 0.f;
        for (int j = threadIdx.x; j < 2048; j += 256) { float v = m0[j]; s += v * v; }
        #pragma unroll
        for (int off = 32; off; off >>= 1) s += __shfl_down(s, off);
        if (lane == 0) fred[wave] = s;
        __syncthreads();
        if (threadIdx.x == 0) {
            double m2 = (double)fred[0] + fred[1] + fred[2] + fred[3];
            double S0 = *(double*)(ws + OFF_S0);
            double lsum2 = 2.0 * (double)NTOT * S0 - 2.0 * m2;
            bws = (float)(lsum2 / ((double)NTOT * NTOT - NTOT) / 4.0);  // /mul^(5//2)
        }
        __syncthreads();
        float bw = bws;
        // ---- exact pair evaluation ----
        const uint2* cand = (const uint2*)(ws + OFF_CAND);
        unsigned gw = blockIdx.x * 4 + wave;
        unsigned nw = gridDim.x * 4;
        double lsum = 0.0;
        for (unsigned i = gw; i < cnt; i += nw) {
            uint2 p = cand[i];
            unsigned a = p.x, b = p.y;   // strict a<b by construction
            const float* ra0 = a < B_ROWS ? src0 + (size_t)a * D0 : tar0 + (size_t)(a - B_ROWS) * D0;
            const float* rb0 = b < B_ROWS ? src0 + (size_t)b * D0 : tar0 + (size_t)(b - B_ROWS) * D0;
            const float* ra1 = a < B_ROWS ? src1 + (size_t)a * D1 : tar1 + (size_t)(a - B_ROWS) * D1;
            const float* rb1 = b < B_ROWS ? src1 + (size_t)b * D1 : tar1 + (size_t)(b - B_ROWS) * D1;
            float d1;
            {
                float2 x = ((const float2*)ra1)[lane];
                float2 y = ((const float2*)rb1)[lane];
                float dx = x.x - y.x, dy = x.y - y.y;
                d1 = dx * dx + dy * dy;
            }
            float d0 = 0.f;
            #pragma unroll
            for (int j = 0; j < 8; j++) {
                float4 x = ((const float4*)ra0)[lane + 64 * j];
                float4 y = ((const float4*)rb0)[lane + 64 * j];
                float dx = x.x - y.x, dy = x.y - y.y, dz = x.z - y.z, dw = x.w - y.w;
                d0 += dx * dx + dy * dy + dz * dz + dw * dw;
            }
            #pragma unroll
            for (int off = 32; off; off >>= 1) {
                d0 += __shfl_down(d0, off);
                d1 += __shfl_down(d1, off);
            }
            if (lane == 0) {
                float k1 = expf(-d1 / 1.68f);
                float k0 = 0.f, bwj = bw;
                #pragma unroll
                for (int j = 0; j < 5; j++) { k0 += expf(-d0 / bwj); bwj *= 2.0f; }
                float sgn = ((a < B_ROWS) == (b < B_ROWS)) ? 1.0f : -1.0f;
                lsum += (double)(2.0f * sgn * k0 * k1);  // x2: (a,b) and (b,a)
            }
        }
        if (lane == 0) red[wave] = lsum;
        __syncthreads();
        if (threadIdx.x == 0)
            atomicAdd((double*)(ws + OFF_ACC), red[0] + red[1] + red[2] + red[3]);
    }
    // ---- completion: last block writes the mean (diag = 8192*5 exactly) ----
    __threadfence();
    if (threadIdx.x == 0) {
        unsigned d = atomicAdd((unsigned*)(ws + OFF_DONE), 1u);
        if (d == gridDim.x - 1) {
            double acc = atomicAdd((double*)(ws + OFF_ACC), 0.0);  // coherent read
            out[0] = (float)((acc + (double)NTOT * 5.0) / ((double)B_ROWS * (double)B_ROWS));
        }
    }
}

extern "C" void kernel_launch(void* const* d_in, const int* in_sizes, int n_in,
                              void* d_out, int out_size, void* d_ws, size_t ws_size,
                              hipStream_t stream) {
    const float* src0 = (const float*)d_in[0];
    const float* src1 = (const float*)d_in[1];
    const float* tar0 = (const float*)d_in[2];
    const float* tar1 = (const float*)d_in[3];
    char* ws = (char*)d_ws;
    unsigned cap = 0;
    if (ws_size > (size_t)OFF_CAND + 8) {
        size_t c = (ws_size - OFF_CAND) / 8;
        if (c > (size_t)4 * 1024 * 1024) c = (size_t)4 * 1024 * 1024;
        cap = (unsigned)c;
    }
    p0a<<<2048, 256, 0, stream>>>(src1, tar1, ws);
    phaseA<<<528, 512, 0, stream>>>(ws, cap);
    phaseB<<<64, 256, 0, stream>>>(src0, src1, tar0, tar1, ws, cap, (float*)d_out);
}

// Round 7
// 117.733 us; speedup vs baseline: 1.0362x; 1.0362x over previous
//
#include <hip/hip_runtime.h>
#include <stdint.h>

#define B_ROWS 4096
#define NTOT   8192
#define D0     2048
#define D1     128
#define TAU    80.0f   // fp8 filter: quantization error on l2 is <~32; true-candidate
                       // threshold of interest is l2<~48 (k1=e^-28); margin is huge.

// ---- workspace layout (bytes) ----
#define OFF_ACC   0        // double  signed sum of OFF-DIAGONAL joint entries
#define OFF_S0    8        // double  sum of squared f0 entries
#define OFF_BW    16       // float   (unused scratch)
#define OFF_CNT   20       // unsigned candidate count
#define OFF_DONE  24       // unsigned phaseB completion counter
#define OFF_M0    32       // float[2048] column sums of f0
#define OFF_SQ1   8320     // float[8192] row sq-norms of f1
#define OFF_T1    41216    // fp8[8192*128] e4m3 copy of f1 (1 MB)
#define OFF_CAND  2138368  // uint2[] candidate pairs
#define ZERO_WORDS 2056    // bytes 0..8223: header + M0

typedef float f32x4 __attribute__((ext_vector_type(4)));
typedef long i64;

#define LDST 136   // bytes per LDS row (128 data + 8 pad; multiple of 8)

// ---- Pass 0a: fp8 convert f1 + row squared norms + ws header zeroing -----
// t1 written NON-TEMPORAL and CLEAN: phaseA's cross-XCD reads are plain
// fetches, not remote-dirty-L2 snoops. sq norms stay exact f32.
__global__ void p0a(const float* __restrict__ src1, const float* __restrict__ tar1, char* __restrict__ ws) {
    if (blockIdx.x == 0) {
        unsigned* w = (unsigned*)ws;
        for (int i = threadIdx.x; i < ZERO_WORDS; i += 256) w[i] = 0;
    }
    int wave = threadIdx.x >> 6, lane = threadIdx.x & 63;
    int row = blockIdx.x * 4 + wave;
    const float2* rp = (const float2*)(row < B_ROWS ? src1 + (size_t)row * D1
                                                    : tar1 + (size_t)(row - B_ROWS) * D1);
    float2 v = rp[lane];
    float sq = v.x * v.x + v.y * v.y;
    #pragma unroll
    for (int off = 32; off; off >>= 1) sq += __shfl_down(sq, off);
    if (lane == 0) ((float*)(ws + OFF_SQ1))[row] = sq;
    int pk = __builtin_amdgcn_cvt_pk_fp8_f32(v.x, v.y, 0, false);  // 2 e4m3 bytes
    __builtin_nontemporal_store((unsigned short)(pk & 0xffff),
        (unsigned short*)(ws + OFF_T1 + (size_t)row * 128 + lane * 2));
}

// ---- Phase A: pairwise l2 on feature-1 via fp8 MFMA, emit candidates -----
// 1D grid of exactly 2080 upper-triangle 128x128 tiles (bj >= bi).
// Single-stage staging of both fp8 strips (32 KB LDS -> 4 blocks/CU), ONE
// barrier, 64 MFMAs/wave (16x16x32_fp8_fp8). l2 = sq_f32[a]+sq_f32[b]-2*dot8.
// Emits STRICT a<b pairs only; diagonal contributes constant 8192*5 (exact:
// dot8(a,a) uses identical quantized vectors but l2 uses f32 norms -> diag
// handled analytically, never computed).
__global__ __launch_bounds__(256, 4) void phaseA(char* __restrict__ ws, unsigned cap) {
    // unmap linear tile id -> (bi, bj), bj >= bi, 64x64 tile grid
    int tid = blockIdx.x;
    int bi = (int)((129.0 - sqrt(129.0 * 129.0 - 8.0 * (double)tid)) * 0.5);
    while (((bi + 1) * (129 - (bi + 1))) / 2 <= tid) bi++;
    while ((bi * (129 - bi)) / 2 > tid) bi--;
    int bj = bi + (tid - (bi * (129 - bi)) / 2);

    __shared__ __align__(16) unsigned char At[128 * LDST];
    __shared__ __align__(16) unsigned char Bt[128 * LDST];
    const uint4* t1 = (const uint4*)(ws + OFF_T1);  // 8 uint4 per 128-B row
    int t = threadIdx.x;
    int lane = t & 63, wave = t >> 6;
    int wm = wave & 1, wn = wave >> 1;
    int quad = lane >> 4;
    int Abase = bi * 128, Bbase = bj * 128;

    // ---- stage: 1024 16B-chunks per strip, 4 per thread per strip ----
    #pragma unroll
    for (int i = 0; i < 4; i++) {
        int q = t + 256 * i;        // 0..1023
        int r = q >> 3, c = q & 7;  // row, chunk-in-row
        uint4 va = t1[(size_t)(Abase + r) * 8 + c];
        *(uint4*)(At + r * LDST + c * 16) = va;
        uint4 vb = t1[(size_t)(Bbase + r) * 8 + c];
        *(uint4*)(Bt + r * LDST + c * 16) = vb;
    }
    __syncthreads();

    f32x4 acc[4][4];
    #pragma unroll
    for (int i = 0; i < 4; i++)
        #pragma unroll
        for (int j = 0; j < 4; j++) acc[i][j] = (f32x4){0.f, 0.f, 0.f, 0.f};

    #pragma unroll
    for (int ks = 0; ks < 4; ks++) {
        int koff = ks * 32 + quad * 8;   // byte offset within 128-B data row
        i64 af[4], bf[4];
        #pragma unroll
        for (int mi = 0; mi < 4; mi++) {
            int row = wm * 64 + mi * 16 + (lane & 15);
            af[mi] = *(const i64*)(At + row * LDST + koff);
        }
        #pragma unroll
        for (int nj = 0; nj < 4; nj++) {
            int row = wn * 64 + nj * 16 + (lane & 15);
            bf[nj] = *(const i64*)(Bt + row * LDST + koff);
        }
        #pragma unroll
        for (int mi = 0; mi < 4; mi++)
            #pragma unroll
            for (int nj = 0; nj < 4; nj++)
                acc[mi][nj] = __builtin_amdgcn_mfma_f32_16x16x32_fp8_fp8(
                    af[mi], bf[nj], acc[mi][nj], 0, 0, 0);
    }

    // epilogue: l2 = sq[a]+sq[b]-2*dot ; emit strict a<b pairs below cutoff
    const float* sq1 = (const float*)(ws + OFF_SQ1);
    unsigned* cnt = (unsigned*)(ws + OFF_CNT);
    uint2* cand = (uint2*)(ws + OFF_CAND);
    f32x4 sqa[4];
    #pragma unroll
    for (int mi = 0; mi < 4; mi++)
        sqa[mi] = *(const f32x4*)&sq1[Abase + wm * 64 + mi * 16 + quad * 4];
    #pragma unroll
    for (int nj = 0; nj < 4; nj++) {
        int b = Bbase + wn * 64 + nj * 16 + (lane & 15);
        float sqb = sq1[b];
        #pragma unroll
        for (int mi = 0; mi < 4; mi++) {
            int abase = Abase + wm * 64 + mi * 16 + quad * 4;
            #pragma unroll
            for (int r = 0; r < 4; r++) {
                int a = abase + r;
                float l2 = sqa[mi][r] + sqb - 2.0f * acc[mi][nj][r];
                if (l2 < TAU && a < b) {
                    unsigned idx = atomicAdd(cnt, 1u);
                    if (idx < cap) cand[idx] = make_uint2((unsigned)a, (unsigned)b);
                }
            }
        }
    }
}

// ---- bwk1: column sums + total sq of f0 — ONLY if candidates exist --------
__global__ void bwk1(const float* __restrict__ src0, const float* __restrict__ tar0, char* __restrict__ ws) {
    if (*(volatile unsigned*)(ws + OFF_CNT) == 0) return;
    int d4 = blockIdx.x * 256 + threadIdx.x;   // float4-column, 0..511
    int rbase = blockIdx.y * 64;
    const float4* base = (const float4*)(rbase < B_ROWS ? src0 + (size_t)rbase * D0
                                                        : tar0 + (size_t)(rbase - B_ROWS) * D0);
    float4 cs = {0.f, 0.f, 0.f, 0.f};
    float sq = 0.f;
    for (int r = 0; r < 64; r++) {
        float4 v = base[(size_t)r * 512 + d4];
        cs.x += v.x; cs.y += v.y; cs.z += v.z; cs.w += v.w;
        sq += v.x * v.x + v.y * v.y + v.z * v.z + v.w * v.w;
    }
    float* m0 = (float*)(ws + OFF_M0);
    atomicAdd(&m0[d4 * 4 + 0], cs.x);
    atomicAdd(&m0[d4 * 4 + 1], cs.y);
    atomicAdd(&m0[d4 * 4 + 2], cs.z);
    atomicAdd(&m0[d4 * 4 + 3], cs.w);
    #pragma unroll
    for (int off = 32; off; off >>= 1) sq += __shfl_down(sq, off);
    __shared__ float red[4];
    int lane = threadIdx.x & 63, wave = threadIdx.x >> 6;
    if (lane == 0) red[wave] = sq;
    __syncthreads();
    if (threadIdx.x == 0)
        atomicAdd((double*)(ws + OFF_S0), (double)(red[0] + red[1] + red[2] + red[3]));
}

// ---- Phase B: exact f32 eval of candidates + bandwidth + final output -----
__global__ void phaseB(const float* __restrict__ src0, const float* __restrict__ src1,
                       const float* __restrict__ tar0, const float* __restrict__ tar1,
                       char* __restrict__ ws, unsigned cap, float* __restrict__ out) {
    __shared__ double red[4];
    __shared__ float fred[4];
    __shared__ float bws;
    unsigned cnt = *(const unsigned*)(ws + OFF_CNT);   // block-uniform
    if (cnt > cap) cnt = cap;
    int lane = threadIdx.x & 63, wave = threadIdx.x >> 6;
    if (cnt > 0) {
        // ---- bandwidth0 = (2n*S0 - 2*||m||^2)/(n^2-n)/4 (per-block) ----
        const float* m0 = (const float*)(ws + OFF_M0);
        float s = 0.f;
        for (int j = threadIdx.x; j < 2048; j += 256) { float v = m0[j]; s += v * v; }
        #pragma unroll
        for (int off = 32; off; off >>= 1) s += __shfl_down(s, off);
        if (lane == 0) fred[wave] = s;
        __syncthreads();
        if (threadIdx.x == 0) {
            double m2 = (double)fred[0] + fred[1] + fred[2] + fred[3];
            double S0 = *(double*)(ws + OFF_S0);
            double lsum2 = 2.0 * (double)NTOT * S0 - 2.0 * m2;
            bws = (float)(lsum2 / ((double)NTOT * NTOT - NTOT) / 4.0);  // /mul^(5//2)
        }
        __syncthreads();
        float bw = bws;
        // ---- exact pair evaluation ----
        const uint2* cand = (const uint2*)(ws + OFF_CAND);
        unsigned gw = blockIdx.x * 4 + wave;
        unsigned nw = gridDim.x * 4;
        double lsum = 0.0;
        for (unsigned i = gw; i < cnt; i += nw) {
            uint2 p = cand[i];
            unsigned a = p.x, b = p.y;   // strict a<b by construction
            const float* ra0 = a < B_ROWS ? src0 + (size_t)a * D0 : tar0 + (size_t)(a - B_ROWS) * D0;
            const float* rb0 = b < B_ROWS ? src0 + (size_t)b * D0 : tar0 + (size_t)(b - B_ROWS) * D0;
            const float* ra1 = a < B_ROWS ? src1 + (size_t)a * D1 : tar1 + (size_t)(a - B_ROWS) * D1;
            const float* rb1 = b < B_ROWS ? src1 + (size_t)b * D1 : tar1 + (size_t)(b - B_ROWS) * D1;
            float d1;
            {
                float2 x = ((const float2*)ra1)[lane];
                float2 y = ((const float2*)rb1)[lane];
                float dx = x.x - y.x, dy = x.y - y.y;
                d1 = dx * dx + dy * dy;
            }
            float d0 = 0.f;
            #pragma unroll
            for (int j = 0; j < 8; j++) {
                float4 x = ((const float4*)ra0)[lane + 64 * j];
                float4 y = ((const float4*)rb0)[lane + 64 * j];
                float dx = x.x - y.x, dy = x.y - y.y, dz = x.z - y.z, dw = x.w - y.w;
                d0 += dx * dx + dy * dy + dz * dz + dw * dw;
            }
            #pragma unroll
            for (int off = 32; off; off >>= 1) {
                d0 += __shfl_down(d0, off);
                d1 += __shfl_down(d1, off);
            }
            if (lane == 0) {
                float k1 = expf(-d1 / 1.68f);
                float k0 = 0.f, bwj = bw;
                #pragma unroll
                for (int j = 0; j < 5; j++) { k0 += expf(-d0 / bwj); bwj *= 2.0f; }
                float sgn = ((a < B_ROWS) == (b < B_ROWS)) ? 1.0f : -1.0f;
                lsum += (double)(2.0f * sgn * k0 * k1);  // x2: (a,b) and (b,a)
            }
        }
        if (lane == 0) red[wave] = lsum;
        __syncthreads();
        if (threadIdx.x == 0)
            atomicAdd((double*)(ws + OFF_ACC), red[0] + red[1] + red[2] + red[3]);
    }
    // ---- completion: last block writes the mean (diag = 8192*5 exactly) ----
    __threadfence();
    if (threadIdx.x == 0) {
        unsigned d = atomicAdd((unsigned*)(ws + OFF_DONE), 1u);
        if (d == gridDim.x - 1) {
            double acc = atomicAdd((double*)(ws + OFF_ACC), 0.0);  // coherent read
            out[0] = (float)((acc + (double)NTOT * 5.0) / ((double)B_ROWS * (double)B_ROWS));
        }
    }
}

extern "C" void kernel_launch(void* const* d_in, const int* in_sizes, int n_in,
                              void* d_out, int out_size, void* d_ws, size_t ws_size,
                              hipStream_t stream) {
    const float* src0 = (const float*)d_in[0];
    const float* src1 = (const float*)d_in[1];
    const float* tar0 = (const float*)d_in[2];
    const float* tar1 = (const float*)d_in[3];
    char* ws = (char*)d_ws;
    unsigned cap = 0;
    if (ws_size > (size_t)OFF_CAND + 8) {
        size_t c = (ws_size - OFF_CAND) / 8;
        if (c > (size_t)4 * 1024 * 1024) c = (size_t)4 * 1024 * 1024;
        cap = (unsigned)c;
    }
    p0a<<<2048, 256, 0, stream>>>(src1, tar1, ws);
    phaseA<<<2080, 256, 0, stream>>>(ws, cap);
    bwk1<<<dim3(2, 128), 256, 0, stream>>>(src0, tar0, ws);
    phaseB<<<64, 256, 0, stream>>>(src0, src1, tar0, tar1, ws, cap, (float*)d_out);
}